// Round 6
// baseline (134.568 us; speedup 1.0000x reference)
//
#include <hip/hip_runtime.h>

// filtfilt butter(4,0.2), 512 rows x T=32768 fp32.
//  - scale/unscale is linear-homogeneous -> cancels exactly -> skipped.
//  - poles |p|max ~0.796: fwd warm-up 32 (~7e-4), bwd warm-up 28 (~2e-3); thr 7e-2.
//  - forward intermediate in registers as packed fp16 pairs (__fp16 ext-vector;
//    __half2 class type fails SROA -> scratch, R3 lesson).
//  - R6: LDS transpose staging. Thread-owned chunks make naive wave accesses
//    256B-strided (64 cache lines per vmem inst -> TA-pipe bound, R5 = 48us at
//    only 2.5 TB/s). Now: wave does lane-contiguous global loads -> LDS (fp32,
//    +2 dw pad per 64 -> thread-side reads are 2-way bank-aliased = free),
//    threads read private spans from LDS; outputs restaged via LDS and stored
//    lane-contiguous. 17.2 KB/block -> 9 single-wave blocks/CU.

typedef __fp16 h2 __attribute__((ext_vector_type(2)));

constexpr int kT    = 32768;
constexpr int kP    = 15;            // padlen
constexpr int kC    = 64;            // outputs per thread
constexpr int kTPB  = 64;            // one wave per block
constexpr int kSpan = kTPB * kC;     // 4096 samples per block
constexpr int kStage = kSpan + 60;   // staged dwords: [-32, +28) window = 4156
constexpr int kLds  = 4288;          // padded LDS size (max addr 4283)

#define B0 0.0048243445989025905f
#define B1 0.019297378395610362f
#define B2 0.028946067593415543f
#define B3 0.019297378395610362f
#define B4 0.0048243445989025905f
#define NA1 2.369513007182038f
#define NA2 (-2.3139884144002064f)
#define NA3 1.0546654058785661f
#define NA4 (-0.18737949236818502f)

// Direct-form II transposed step.
#define STEP(xv) do { \
    y  = fmaf(B0, (xv), z1); \
    z1 = fmaf(NA1, y, fmaf(B1, (xv), z2)); \
    z2 = fmaf(NA2, y, fmaf(B2, (xv), z3)); \
    z3 = fmaf(NA3, y, fmaf(B3, (xv), z4)); \
    z4 = fmaf(NA4, y, B4 * (xv)); \
} while (0)

// two steps -> one packed fp16 pair (v_cvt_pkrtz_f16_f32)
#define PACK2(va, vb, DST) do { \
    STEP(va); float _t = y; \
    STEP(vb); DST = __builtin_amdgcn_cvt_pkrtz(_t, y); \
} while (0)

__device__ __forceinline__ int pad_addr(int m) { return m + 2 * (m >> 6); }

__global__ __launch_bounds__(kTPB, 2)
void filtfilt_kernel(const float* __restrict__ x, float* __restrict__ out) {
    __shared__ float lds[kLds];      // 17152 B -> 9 blocks/CU
    const int tix = threadIdx.x;
    const int row = blockIdx.x >> 3;          // 8 blocks per row
    const int blk = blockIdx.x & 7;
    const int s0  = blk * kSpan;
    const bool rowfirst = (blk == 0);
    const bool rowlast  = (blk == 7);
    const float* __restrict__ xr = x + (size_t)row * kT;
    float* __restrict__ outr     = out + (size_t)row * kT;

    // ---------------- stage: coalesced global -> LDS (fp32, padded) --------
    #pragma unroll
    for (int j = 0; j < 17; ++j) {
        const int m = 256 * j + 4 * tix;      // block-local dword index
        if (m < kStage) {
            int g = s0 - 32 + m;              // row-local dword index
            g = g < 0 ? 0 : g;
            g = g > (kT - 4) ? (kT - 4) : g;  // clamped dups land in unused slots
            const float4 v = *(const float4*)(xr + g);
            const int a = pad_addr(m);        // even; lanes {i,i+8} share banks: 2-way, free
            *(float2*)&lds[a]     = float2{v.x, v.y};
            *(float2*)&lds[a + 2] = float2{v.z, v.w};
        }
    }
    __syncthreads();

    // thread-local LDS geometry: span [64*tix, 64*tix+124) maps to
    // addr [base, base+64) then [base+66, base+126) (pad gap of 2 at +64).
    const int base = 66 * tix;

    h2 arc[kC / 2];   // stored fwd samples
    h2 wu[14];        // bwd warm-up samples (last chunk: 15 right-ext tail)
    float z1 = 0.f, z2 = 0.f, z3 = 0.f, z4 = 0.f, y;

    // ---------------- forward warm-up ----------------
    if (rowfirst && tix == 0) {
        // exact: left odd-extension (2x[0]-x[15-e]), x[0..16) at addr 32..48
        float xa[16];
        #pragma unroll
        for (int k = 0; k < 8; ++k) {
            float2 p = *(const float2*)&lds[32 + 2 * k];
            xa[2 * k] = p.x; xa[2 * k + 1] = p.y;
        }
        #pragma unroll
        for (int e = 0; e < kP; ++e) {
            float xv = fmaf(2.f, xa[0], -xa[kP - e]);
            STEP(xv);
        }
    } else {
        // approx: 32 warm-up samples, zero ICs (pole decay ~7e-4)
        #pragma unroll
        for (int k = 0; k < 32; k += 2) {
            float2 p = *(const float2*)&lds[base + k];
            STEP(p.x); STEP(p.y);
        }
    }

    // ---------------- forward main: 64 samples -> arc ----------------
    #pragma unroll
    for (int k = 0; k < 32; k += 2) {
        float2 p = *(const float2*)&lds[base + 32 + k];
        PACK2(p.x, p.y, arc[k >> 1]);
    }
    #pragma unroll
    for (int k = 32; k < 64; k += 2) {
        float2 p = *(const float2*)&lds[base + 34 + k];   // +2 pad crossing
        PACK2(p.x, p.y, arc[k >> 1]);
    }

    // ---------------- forward continue: bwd warm-up samples ----------------
    if (rowlast && tix == 63) {
        // exact: 15 right-odd-extension samples; x[T-16..T) at addr 4240..4256
        float xa[16];
        #pragma unroll
        for (int k = 0; k < 8; ++k) {
            float2 p = *(const float2*)&lds[4240 + 2 * k];
            xa[2 * k] = p.x; xa[2 * k + 1] = p.y;
        }
        float pend = 0.f;
        #pragma unroll
        for (int r = 0; r < 15; ++r) {
            float xv = fmaf(2.f, xa[15], -xa[14 - r]);    // 2x[T-1]-x[T-2-r]
            STEP(xv);
            if ((r & 1) == 0) pend = y;
            else wu[r >> 1] = __builtin_amdgcn_cvt_pkrtz(pend, y);
        }
        wu[7] = __builtin_amdgcn_cvt_pkrtz(pend, pend);   // r=14 in .x
    } else {
        #pragma unroll
        for (int k = 0; k < 28; k += 2) {
            float2 p = *(const float2*)&lds[base + 98 + k];
            PACK2(p.x, p.y, wu[k >> 1]);
        }
    }
    __syncthreads();   // all forward LDS reads done before output overwrite

    // ---------------- backward warm-up (zero ICs; exact at signal end) -----
    z1 = z2 = z3 = z4 = 0.f;
    if (rowlast && tix == 63) {
        { float a = (float)wu[7].x; STEP(a); }            // tail sample r=14
        #pragma unroll
        for (int k = 6; k >= 0; --k) {
            float a = (float)wu[k].y; STEP(a);
            float b = (float)wu[k].x; STEP(b);
        }
    } else {
        #pragma unroll
        for (int k = 13; k >= 0; --k) {
            float a = (float)wu[k].y; STEP(a);
            float b = (float)wu[k].x; STEP(b);
        }
    }

    // ---------------- backward main: 64 outputs -> LDS (descending) --------
    #pragma unroll
    for (int k = 62; k >= 0; k -= 2) {
        float v1 = (float)arc[k >> 1].y; STEP(v1); float oy = y;
        float v0 = (float)arc[k >> 1].x; STEP(v0);
        *(float2*)&lds[base + k] = float2{y, oy};
    }
    __syncthreads();

    // ---------------- coalesced store: LDS -> global ----------------
    #pragma unroll
    for (int j2 = 0; j2 < 32; ++j2) {
        const int q = 128 * j2 + 2 * tix;                 // block-local out dword
        const int a = 66 * (q >> 6) + (q & 63);           // owner-thread layout
        float2 p = *(const float2*)&lds[a];
        *(float2*)(outr + s0 + q) = p;
    }
}

extern "C" void kernel_launch(void* const* d_in, const int* in_sizes, int n_in,
                              void* d_out, int out_size, void* d_ws, size_t ws_size,
                              hipStream_t stream) {
    const float* x = (const float*)d_in[0];
    float* out     = (float*)d_out;
    const int rows   = in_sizes[0] / kT;      // 512
    const int blocks = rows * 8;              // 4096 single-wave blocks
    filtfilt_kernel<<<blocks, kTPB, 0, stream>>>(x, out);
}